// Round 9
// baseline (307.981 us; speedup 1.0000x reference)
//
#include <hip/hip_runtime.h>
#include <stdint.h>

// B=16, S=2048, D=128 attention, per-query scale folded into Q (with log2e),
// online softmax in exp2 domain, exact JAX partitionable-threefry dropout
// (key 42, p=0.1), @V.
// Round 9: 1024-thread blocks (16 waves = 4 waves/SIMD) at TQ=128 —
// 8 q-groups x 2 key-phases, one 16-row subtile per wave (r6 shape, low
// VGPR) + r8 pipeline (double-buffered K/V LDS, single barrier/iter,
// 3-stage register prefetch, threefry hoisted into the MFMA shadow).
// Rationale: r8 showed ~60% of cycles are latency stalls unhidable at
// 2 waves/SIMD; this doubles the independent streams per SIMD.

#define B_ 16
#define S_ 2048
#define D_ 128
#define TQ 128    // q rows per block (8 groups x 16)
#define TK 64     // keys staged per iteration (each kph-wave consumes 32)
#define NT (S_ / TK)
#define KSTR 136  // f16 stride for K rows (128+8): 272B, 16B-aligned
#define VSTR 72   // f16 stride for V^T rows (64+8): 144B
#define PSTR 40   // f16 stride for per-wave P rows (32+8): 80B

typedef float f32x4 __attribute__((ext_vector_type(4)));
typedef _Float16 f16x8 __attribute__((ext_vector_type(8)));
typedef _Float16 f16x2 __attribute__((ext_vector_type(2)));

union F32R { float4 q[2]; float f[8]; };

// DPP row_ror reductions over 16-lane row groups.
#define DPP_ROR(x, ctrl) \
  __int_as_float(__builtin_amdgcn_update_dpp(0, __float_as_int(x), (ctrl), 0xf, 0xf, true))
__device__ __forceinline__ float row16_max(float x) {
  x = fmaxf(x, DPP_ROR(x, 0x128));
  x = fmaxf(x, DPP_ROR(x, 0x124));
  x = fmaxf(x, DPP_ROR(x, 0x122));
  x = fmaxf(x, DPP_ROR(x, 0x121));
  return x;
}
__device__ __forceinline__ float row16_sum(float x) {
  x += DPP_ROR(x, 0x128);
  x += DPP_ROR(x, 0x124);
  x += DPP_ROR(x, 0x122);
  x += DPP_ROR(x, 0x121);
  return x;
}

// threefry2x32, 20 rounds, key = (0, 42)  [jax.random.key(42)]
__device__ __forceinline__ uint2 threefry2x32_0_42(uint32_t x0, uint32_t x1) {
  const uint32_t k0 = 0u, k1 = 42u;
  const uint32_t k2 = 0x1BD11BDAu ^ k0 ^ k1;
  x0 += k0; x1 += k1;
#define TFR(r) { x0 += x1; x1 = __builtin_rotateleft32(x1, r); x1 ^= x0; }
  TFR(13) TFR(15) TFR(26) TFR(6)
  x0 += k1; x1 += k2 + 1u;
  TFR(17) TFR(29) TFR(16) TFR(24)
  x0 += k2; x1 += k0 + 2u;
  TFR(13) TFR(15) TFR(26) TFR(6)
  x0 += k0; x1 += k1 + 3u;
  TFR(17) TFR(29) TFR(16) TFR(24)
  x0 += k1; x1 += k2 + 4u;
  TFR(13) TFR(15) TFR(26) TFR(6)
  x0 += k2; x1 += k0 + 5u;
#undef TFR
  return make_uint2(x0, x1);
}

// HW-verified (round 2): partitionable path, counter (0, j), xor-fold.
__device__ __forceinline__ uint32_t jax_bits(uint32_t j) {
  const uint2 tf = threefry2x32_0_42(0u, j);
  return tf.x ^ tf.y;
}

__global__ __launch_bounds__(1024, 4)
void attn_mfma_kernel(const float* __restrict__ Q, const float* __restrict__ K,
                      const float* __restrict__ V, const float* __restrict__ ISF,
                      const float* __restrict__ DP, float* __restrict__ OUT) {
  extern __shared__ __align__(16) char smem[];
  _Float16* const sK0  = (_Float16*)smem;               // 64x136 f16 = 17408 B
  _Float16* const sK1  = (_Float16*)(smem + 17408);
  _Float16* const sVT0 = (_Float16*)(smem + 34816);     // 128x72 f16 = 18432 B
  _Float16* const sVT1 = (_Float16*)(smem + 53248);
  _Float16* const sP   = (_Float16*)(smem + 71680);     // 16 x 16x40 = 20480 B
  // merge overlay (after final barrier):
  float* const sO1 = (float*)smem;                      // 128x128 f32 = 65536 B
  float* const sM1 = (float*)(smem + 65536);            // 128 f32
  float* const sL1 = (float*)(smem + 66048);            // 128 f32

  const int t    = threadIdx.x;
  const int lane = t & 63;
  const int l15  = lane & 15;
  const int quad = lane >> 4;
  const int w    = t >> 6;       // 0..15
  const int qg   = w & 7;        // q-group (16 rows)
  const int kph  = w >> 3;       // key phase: 0 = keys [0,32), 1 = [32,64)
  const int b    = blockIdx.y;
  const int qb   = blockIdx.x * TQ + qg * 16;

  const float kp = 1.0f - DP[0];
  const uint32_t TH9 = (__float_as_uint(1.0f + kp) & 0x7FFFFFu) << 9;

  float m_[4], l_[4];
  uint32_t jq[4];
  #pragma unroll
  for (int r = 0; r < 4; ++r) {
    m_[r] = -INFINITY;
    l_[r] = 0.0f;
    jq[r] = ((uint32_t)b << 22)
          + (uint32_t)(qb + quad * 4 + r) * (uint32_t)S_;
  }

  // ---- Q fragments, f16, per-query 1/isf and log2(e) folded in ----
  f16x8 qf[4];
  {
    const int qrow = qb + l15;
    const float qs = 1.4426950408889634f / ISF[b * S_ + qrow];
    const float* qp = Q + ((size_t)(b * S_ + qrow)) * D_;
    #pragma unroll
    for (int c = 0; c < 4; ++c) {
      const float4 a  = *(const float4*)(qp + c * 32 + quad * 8);
      const float4 d2 = *(const float4*)(qp + c * 32 + quad * 8 + 4);
      const float xs[8] = {a.x, a.y, a.z, a.w, d2.x, d2.y, d2.z, d2.w};
      f16x8 h;
      #pragma unroll
      for (int j = 0; j < 8; ++j) h[j] = (_Float16)(xs[j] * qs);
      qf[c] = h;
    }
  }

  f32x4 accO[8];
  #pragma unroll
  for (int i = 0; i < 8; ++i) accO[i] = (f32x4){0.f, 0.f, 0.f, 0.f};

  _Float16* const pwv = &sP[w * 16 * PSTR];

  // staging decomposition (1024 threads)
  const int krow = t >> 4, kcol = (t & 15) * 8;        // K: 64 rows x 128
  const int vp = t & 31, dseg = (t >> 5) * 4;          // V: 32 key-pairs x 4 d

  F32R kreg;            // prefetched K floats (8/thread)
  F32R vreg;            // prefetched V floats (4+4/thread)

#define ISSUE_LOADS(KT)                                                        \
  {                                                                            \
    const float4* gk4 = (const float4*)(K +                                    \
        ((size_t)(b * S_ + (KT) * TK + krow)) * D_ + kcol);                    \
    kreg.q[0] = gk4[0];                                                        \
    kreg.q[1] = gk4[1];                                                        \
    const float4* gv4 = (const float4*)(V +                                    \
        ((size_t)(b * S_ + (KT) * TK + 2 * vp)) * D_ + dseg);                  \
    vreg.q[0] = gv4[0];                                                        \
    vreg.q[1] = gv4[32];  /* +128 floats = next key row */                     \
  }

#define CONVERT_TO(KB, VB)                                                     \
  {                                                                            \
    f16x8 h;                                                                   \
    _Pragma("unroll") for (int j = 0; j < 8; ++j)                              \
      h[j] = (_Float16)kreg.f[j];                                              \
    *(f16x8*)&(KB)[krow * KSTR + kcol] = h;                                    \
    _Pragma("unroll") for (int d = 0; d < 4; ++d) {                            \
      f16x2 h2 = {(_Float16)vreg.f[d], (_Float16)vreg.f[4 + d]};               \
      *(f16x2*)&(VB)[(dseg + d) * VSTR + 2 * vp] = h2;                         \
    }                                                                          \
  }

  // ---- pipeline prologue: tile 0 -> buf0; issue loads for tile 1 ----
  ISSUE_LOADS(0)
  CONVERT_TO(sK0, sVT0)
  ISSUE_LOADS(1)
  __syncthreads();

  for (int kt = 0; kt < NT; ++kt) {
    const int cur = kt & 1;
    _Float16* const sKc = cur ? sK1 : sK0;
    _Float16* const sVc = cur ? sVT1 : sVT0;

    // ---- QK^T: 16 q-rows x 32 keys (this wave's phase) ----
    f32x4 s[2];
    #pragma unroll
    for (int n = 0; n < 2; ++n) {
      f32x4 acc = (f32x4){0.f, 0.f, 0.f, 0.f};
      #pragma unroll
      for (int c = 0; c < 4; ++c) {
        const f16x8 bh = *(const f16x8*)&sKc[(kph * 32 + n * 16 + l15) * KSTR
                                             + c * 32 + quad * 8];
        acc = __builtin_amdgcn_mfma_f32_16x16x32_f16(qf[c], bh, acc, 0, 0, 0);
      }
      s[n] = acc;
    }

    // ---- dropout bits (independent of scores; fills the MFMA shadow) ----
    uint32_t rb[2][4];
    #pragma unroll
    for (int n = 0; n < 2; ++n) {
      const uint32_t jcol = (uint32_t)(kt * TK + kph * 32 + n * 16 + l15);
      #pragma unroll
      for (int r = 0; r < 4; ++r)
        rb[n][r] = jax_bits(jq[r] + jcol);
    }

    // ---- online softmax (exp2 domain) ----
    float mx[4];
    int changed = 0;
    #pragma unroll
    for (int r = 0; r < 4; ++r) {
      mx[r] = row16_max(fmaxf(s[0][r], s[1][r]));
      changed |= (mx[r] > m_[r]);
    }
    if (__ballot(changed) != 0ull) {
      #pragma unroll
      for (int r = 0; r < 4; ++r) {
        const float mnew = fmaxf(m_[r], mx[r]);
        const float alpha = __builtin_amdgcn_exp2f(m_[r] - mnew);
        m_[r] = mnew;
        l_[r] *= alpha;
        #pragma unroll
        for (int i = 0; i < 8; ++i) accO[i][r] *= alpha;
      }
    }
    #pragma unroll
    for (int r = 0; r < 4; ++r) {
      const float p0 = __builtin_amdgcn_exp2f(s[0][r] - m_[r]);
      const float p1 = __builtin_amdgcn_exp2f(s[1][r] - m_[r]);
      s[0][r] = p0;
      s[1][r] = p1;
      l_[r] += row16_sum(p0 + p1);
    }

    // ---- masked f16 P into wave-private LDS ----
    #pragma unroll
    for (int n = 0; n < 2; ++n) {
      const int col = n * 16 + l15;
      #pragma unroll
      for (int r = 0; r < 4; ++r) {
        const float pf = (rb[n][r] < TH9) ? s[n][r] : 0.0f;
        pwv[(quad * 4 + r) * PSTR + col] = (_Float16)pf;
      }
    }
    __threadfence_block();   // order cross-lane P writes before A-frag reads

    // ---- PV: O[16x128] += P[16x32] * V[32x128] ----
    {
      const f16x8 ap = *(const f16x8*)&pwv[l15 * PSTR + quad * 8];
      #pragma unroll
      for (int d8 = 0; d8 < 8; ++d8) {
        const f16x8 bv = *(const f16x8*)&sVc[(d8 * 16 + l15) * VSTR
                                             + kph * 32 + quad * 8];
        accO[d8] = __builtin_amdgcn_mfma_f32_16x16x32_f16(ap, bv, accO[d8], 0, 0, 0);
      }
    }

    // ---- pipeline advance: convert kt+1 into other buffer; load kt+2 ----
    if (kt + 1 < NT) {
      _Float16* const sKn = cur ? sK0 : sK1;
      _Float16* const sVn = cur ? sVT0 : sVT1;
      CONVERT_TO(sKn, sVn)
      if (kt + 2 < NT) ISSUE_LOADS(kt + 2)
    }
    __syncthreads();   // single barrier per iteration
  }
#undef ISSUE_LOADS
#undef CONVERT_TO

  // ---- merge the two key-phase waves of each q-group ----
  if (kph == 1) {
    if (l15 == 0) {
      #pragma unroll
      for (int r = 0; r < 4; ++r) {
        const int gr = qg * 16 + quad * 4 + r;
        sM1[gr] = m_[r];
        sL1[gr] = l_[r];
      }
    }
    #pragma unroll
    for (int d8 = 0; d8 < 8; ++d8)
      #pragma unroll
      for (int r = 0; r < 4; ++r) {
        const int gr = qg * 16 + quad * 4 + r;
        sO1[gr * D_ + d8 * 16 + l15] = accO[d8][r];
      }
  }
  __syncthreads();
  if (kph == 0) {
    float a0s[4], a1s[4];
    #pragma unroll
    for (int r = 0; r < 4; ++r) {
      const int gr = qg * 16 + quad * 4 + r;
      const float m1  = sM1[gr];
      const float l1v = sL1[gr];
      const float mf = fmaxf(m_[r], m1);
      const float a0 = __builtin_amdgcn_exp2f(m_[r] - mf);
      const float a1 = __builtin_amdgcn_exp2f(m1 - mf);
      const float inv = 1.0f / ((a0 * l_[r] + a1 * l1v) * kp);
      a0s[r] = a0 * inv;
      a1s[r] = a1 * inv;
    }
    #pragma unroll
    for (int d8 = 0; d8 < 8; ++d8)
      #pragma unroll
      for (int r = 0; r < 4; ++r) {
        const int gr = qg * 16 + quad * 4 + r;
        const float o1 = sO1[gr * D_ + d8 * 16 + l15];
        OUT[((size_t)(b * S_ + blockIdx.x * TQ + gr)) * D_ + d8 * 16 + l15] =
            accO[d8][r] * a0s[r] + o1 * a1s[r];
      }
  }
}

extern "C" void kernel_launch(void* const* d_in, const int* in_sizes, int n_in,
                              void* d_out, int out_size, void* d_ws, size_t ws_size,
                              hipStream_t stream) {
  const float* q   = (const float*)d_in[0];
  const float* k   = (const float*)d_in[1];
  const float* v   = (const float*)d_in[2];
  const float* isf = (const float*)d_in[3];
  const float* dp  = (const float*)d_in[4];
  float* out = (float*)d_out;

  dim3 grid(S_ / TQ, B_);
  attn_mfma_kernel<<<grid, dim3(1024), 92160, stream>>>(q, k, v, isf, dp, out);
}